// Round 1
// baseline (28.736 us; speedup 1.0000x reference)
//
#include <hip/hip_runtime.h>

#define BB 32
#define LL 512
#define HH 1024
#define MAXH 32
#define MAXHL 12
#define HROWS (MAXH * MAXHL)  // 384

// ---------------------------------------------------------------------------
// Kernel A: per-batch scan over segment -> inverse maps
//   src_q[b*L + j]       = source position of j-th question token, or -1
//   src_h[b*384 + r*12+p]= source position of header run r, pos p, or -1
// One block per batch, 64 threads (1 wave), each lane owns 8 positions.
// ---------------------------------------------------------------------------
__global__ __launch_bounds__(64) void meta_kernel(const int* __restrict__ seg,
                                                  int* __restrict__ src_q,
                                                  int* __restrict__ src_h) {
    __shared__ int lq[LL];
    __shared__ int lh[HROWS];
    const int b = blockIdx.x;
    const int t = threadIdx.x;  // 0..63

    for (int k = t; k < LL; k += 64) lq[k] = -1;
    for (int k = t; k < HROWS; k += 64) lh[k] = -1;
    __syncthreads();

    // each lane loads 8 consecutive seg values (coalesced across the wave)
    int s[8];
    const int base = b * LL + t * 8;
#pragma unroll
    for (int k = 0; k < 8; ++k) s[k] = seg[base + k];

    // is_h of my last element -> shfl to the right neighbor for run_start
    int last_ish = (s[7] == 1) ? 1 : 0;
    int prev_from_left = __shfl_up(last_ish, 1);
    if (t == 0) prev_from_left = 0;

    // local aggregates over my 8 elements
    int qc = 0, rc = 0, mstart = -1;
    {
        int ph = prev_from_left;
#pragma unroll
        for (int k = 0; k < 8; ++k) {
            int ish = (s[k] == 1);
            if (s[k] == 2) qc++;
            if (ish && !ph) { rc++; mstart = t * 8 + k; }
            ph = ish;
        }
    }

    // inclusive scan across 64 lanes: (sum, sum, max)
    int iq = qc, ir = rc, im = mstart;
    for (int off = 1; off < 64; off <<= 1) {
        int uq = __shfl_up(iq, off);
        int ur = __shfl_up(ir, off);
        int um = __shfl_up(im, off);
        if (t >= off) {
            iq += uq;
            ir += ur;
            im = max(im, um);
        }
    }
    int exq = iq - qc;                    // exclusive sum of question count
    int exr = ir - rc;                    // exclusive sum of run-start count
    int exm = __shfl_up(im, 1);           // exclusive max of last run-start
    if (t == 0) exm = -1;

    // second serial pass: emit inverse maps
    {
        int qpos = exq, runs = exr, last = exm, ph = prev_from_left;
#pragma unroll
        for (int k = 0; k < 8; ++k) {
            int i = t * 8 + k;
            int ish = (s[k] == 1);
            if (ish && !ph) { runs++; last = i; }
            if (ish) {
                int pos = i - last;
                int rid = runs - 1;
                if (pos < MAXHL && rid < MAXH) lh[rid * MAXHL + pos] = i;
            }
            if (s[k] == 2) { lq[qpos] = i; qpos++; }
            ph = ish;
        }
    }
    __syncthreads();

    for (int k = t; k < LL; k += 64) src_q[b * LL + k] = lq[k];
    for (int k = t; k < HROWS; k += 64) src_h[b * HROWS + k] = lh[k];
}

// ---------------------------------------------------------------------------
// Kernel B: one block per output row (1024 floats). Copy enc row or zeros.
// Rows [0, B*L)          -> question_hidden
// Rows [B*L, B*L+B*384)  -> headers
// ---------------------------------------------------------------------------
__global__ __launch_bounds__(256) void copy_kernel(const float* __restrict__ enc,
                                                   const int* __restrict__ src_q,
                                                   const int* __restrict__ src_h,
                                                   float* __restrict__ out) {
    const int bid = blockIdx.x;
    const int t = threadIdx.x;  // 0..255, one float4 each

    int b, src;
    long long outOff;
    if (bid < BB * LL) {
        b = bid >> 9;  // / LL
        src = src_q[bid];
        outOff = (long long)bid * HH;
    } else {
        int hb = bid - BB * LL;
        b = hb / HROWS;
        src = src_h[hb];
        outOff = (long long)BB * LL * HH + (long long)hb * HH;
    }

    float4* dst = reinterpret_cast<float4*>(out + outOff) + t;
    if (src >= 0) {
        const float4* sp =
            reinterpret_cast<const float4*>(enc + ((long long)(b * LL + src)) * HH) + t;
        *dst = *sp;
    } else {
        *dst = make_float4(0.f, 0.f, 0.f, 0.f);
    }
}

extern "C" void kernel_launch(void* const* d_in, const int* in_sizes, int n_in,
                              void* d_out, int out_size, void* d_ws, size_t ws_size,
                              hipStream_t stream) {
    const float* enc = (const float*)d_in[0];
    const int* seg = (const int*)d_in[1];
    float* out = (float*)d_out;

    int* src_q = (int*)d_ws;             // B*L ints
    int* src_h = src_q + BB * LL;        // B*384 ints

    meta_kernel<<<BB, 64, 0, stream>>>(seg, src_q, src_h);
    copy_kernel<<<BB * LL + BB * HROWS, 256, 0, stream>>>(enc, src_q, src_h, out);
}

// Round 2
// 25.088 us; speedup vs baseline: 1.1454x; 1.1454x over previous
//
#include <hip/hip_runtime.h>

#define BB 32
#define LL 512
#define HH 1024
#define MAXH 32
#define MAXHL 12
#define HROWS (MAXH * MAXHL)  // 384
#define RPB 4                 // rows per block

#define NQG (LL / RPB)        // 128 q-row groups per batch
#define NHG (HROWS / RPB)     // 96 header-row groups per batch
#define QBLOCKS (BB * NQG)    // 4096
#define HBLOCKS (BB * NHG)    // 3072

// One fused kernel. Each block owns 4 consecutive output rows of one batch.
// Wave 0 re-derives the segment scan for its batch (seg is 64 KB total ->
// cache-resident) and resolves the 4 source positions; then all 256 threads
// copy 4 rows (16 KB contiguous writes).
__global__ __launch_bounds__(256) void fused_kernel(const float* __restrict__ enc,
                                                    const int* __restrict__ seg,
                                                    float* __restrict__ out) {
    __shared__ int s_src[RPB];
    const int bid = blockIdx.x;
    const int t = threadIdx.x;

    // decode block -> (batch, mode, first row)
    int b, qmode, idx0;           // q: idx0 = first j; h: idx0 = first r*12+p
    long long outRow0;            // first output row (global, rows of H floats)
    if (bid < QBLOCKS) {
        b = bid >> 7;                       // / NQG
        idx0 = (bid & (NQG - 1)) * RPB;
        qmode = 1;
        outRow0 = (long long)b * LL + idx0;
    } else {
        int hb = bid - QBLOCKS;
        b = hb / NHG;
        idx0 = (hb % NHG) * RPB;
        qmode = 0;
        outRow0 = (long long)BB * LL + (long long)b * HROWS + idx0;
    }

    if (t < 64) {
        if (t < RPB) s_src[t] = -1;
        // each lane owns 8 consecutive seg positions
        int s[8];
        const int base = b * LL + t * 8;
#pragma unroll
        for (int k = 0; k < 8; ++k) s[k] = seg[base + k];

        int last_ish = (s[7] == 1) ? 1 : 0;
        int prev_from_left = __shfl_up(last_ish, 1);
        if (t == 0) prev_from_left = 0;

        // local aggregates: question count, run-start count, last run-start pos
        int qc = 0, rc = 0, mstart = -1;
        {
            int ph = prev_from_left;
#pragma unroll
            for (int k = 0; k < 8; ++k) {
                int ish = (s[k] == 1);
                if (s[k] == 2) qc++;
                if (ish && !ph) { rc++; mstart = t * 8 + k; }
                ph = ish;
            }
        }

        // inclusive wave scan of (sum, sum, max)
        int iq = qc, ir = rc, im = mstart;
#pragma unroll
        for (int off = 1; off < 64; off <<= 1) {
            int uq = __shfl_up(iq, off);
            int ur = __shfl_up(ir, off);
            int um = __shfl_up(im, off);
            if (t >= off) {
                iq += uq;
                ir += ur;
                im = max(im, um);
            }
        }
        int exq = iq - qc;
        int exr = ir - rc;
        int exm = __shfl_up(im, 1);
        if (t == 0) exm = -1;

        // replay: resolve the 4 rows this block needs
        {
            int qpos = exq, runs = exr, last = exm, ph = prev_from_left;
#pragma unroll
            for (int k = 0; k < 8; ++k) {
                int i = t * 8 + k;
                int ish = (s[k] == 1);
                if (ish && !ph) { runs++; last = i; }
                if (qmode) {
                    if (s[k] == 2) {
                        int d = qpos - idx0;
                        if (d >= 0 && d < RPB) s_src[d] = i;
                        qpos++;
                    }
                } else if (ish) {
                    int pos = i - last;
                    int rid = runs - 1;
                    if (pos < MAXHL && rid < MAXH) {
                        int d = rid * MAXHL + pos - idx0;
                        if (d >= 0 && d < RPB) s_src[d] = i;
                    }
                }
                ph = ish;
            }
        }
    }
    __syncthreads();

    // copy 4 rows; thread t moves one float4 per row
    const long long encBase = (long long)b * LL * HH;
#pragma unroll
    for (int r = 0; r < RPB; ++r) {
        int src = s_src[r];
        float4* dst = reinterpret_cast<float4*>(out + (outRow0 + r) * HH) + t;
        if (src >= 0) {
            const float4* sp = reinterpret_cast<const float4*>(enc + encBase + (long long)src * HH) + t;
            *dst = *sp;
        } else {
            *dst = make_float4(0.f, 0.f, 0.f, 0.f);
        }
    }
}

extern "C" void kernel_launch(void* const* d_in, const int* in_sizes, int n_in,
                              void* d_out, int out_size, void* d_ws, size_t ws_size,
                              hipStream_t stream) {
    const float* enc = (const float*)d_in[0];
    const int* seg = (const int*)d_in[1];
    float* out = (float*)d_out;
    fused_kernel<<<QBLOCKS + HBLOCKS, 256, 0, stream>>>(enc, seg, out);
}